// Round 1
// baseline (365.782 us; speedup 1.0000x reference)
//
#include <hip/hip_runtime.h>

#define BB 8
#define TT 4096
#define DD 1024
#define KK 64
#define L1SEG 256     // t-steps per K1 block
#define DT 256        // channels per K1 block
#define TC 16         // t-rows per K2 block

// Kernel 1: f64 sliding-window recurrence -> spike bits (packed u64 per 64 channels)
__global__ __launch_bounds__(256) void lif_spike_kernel(
    const float* __restrict__ x, const float* __restrict__ threshold,
    const float* __restrict__ tau, const float* __restrict__ v0p,
    unsigned long long* __restrict__ masks)
{
    __shared__ float cbuf[KK][DT];   // per-thread private 64-deep x history (own column only)
    const int tid   = threadIdx.x;
    const int tseg  = blockIdx.x;
    const int dtile = blockIdx.y;
    const int b     = blockIdx.z;
    const int d     = dtile * DT + tid;
    const int t0    = tseg * L1SEG;

    double tc = (double)tau[d];
    tc = tc < 0.001 ? 0.001 : (tc > 0.999 ? 0.999 : tc);   // clip in f64, matching np-f64 ref
    const double ltau = log(tc);
    const double c64  = exp(64.0 * ltau);                  // tau^64
    const double thr  = (double)threshold[d];
    const double v0   = (double)v0p[d];
    double pw  = exp((double)(t0 + 1) * ltau);             // tau^(t0+1) for the v-decay term
    double acc = 0.0;

    const float* xb = x + ((size_t)b * TT) * DD + d;

    // warm-up: 64 steps fill the window history and the running sum
    for (int t = t0 - KK; t < t0; ++t) {
        float xv = (t >= 0) ? xb[(size_t)t * DD] : 0.0f;
        cbuf[t & (KK - 1)][tid] = xv;
        acc = fma(tc, acc, (double)xv);
    }

    const int lane = tid & 63;
    const int wg   = dtile * 4 + (tid >> 6);               // which of 16 mask words per row
    unsigned long long* mrow = masks + ((size_t)b * TT) * 16 + wg;

    #pragma unroll 8
    for (int t = t0; t < t0 + L1SEG; ++t) {
        float xv = xb[(size_t)t * DD];
        int slot = t & (KK - 1);
        float oldv = cbuf[slot][tid];
        cbuf[slot][tid] = xv;
        acc = fma(tc, acc, (double)xv);                    // acc = tau*acc + x[t]
        acc = fma(-c64, (double)oldv, acc);                //     - tau^64 * x[t-64]
        double vint = fma(v0, pw, acc);                    // + v * tau^(t+1)
        pw *= tc;
        unsigned long long m = __ballot(vint >= thr);
        if (lane == 0) mrow[(size_t)t * 16] = m;
    }
}

// Kernel 2: popcount -> denom -> normalized float4 output
__global__ __launch_bounds__(256) void lif_norm_kernel(
    const unsigned long long* __restrict__ masks,
    float* __restrict__ out)
{
    __shared__ unsigned long long mw[TC * 16];
    __shared__ float rcp[TC];
    const int tid    = threadIdx.x;
    const int tchunk = blockIdx.x;
    const int b      = blockIdx.y;
    const int tbase  = tchunk * TC;

    mw[tid] = masks[((size_t)b * TT + tbase) * 16 + tid];  // 256 consecutive u64, coalesced
    __syncthreads();

    if (tid < TC) {
        int cnt = 0;
        #pragma unroll
        for (int w = 0; w < 16; ++w) cnt += __popcll(mw[tid * 16 + w]);
        float denom = fmaxf((float)cnt, 1.0f);
        rcp[tid] = 1.0f / denom;
    }
    __syncthreads();

    // thread tid owns channels d = tid*4 .. tid*4+3
    float4* outb = (float4*)(out + ((size_t)b * TT + tbase) * DD) + tid;
    #pragma unroll
    for (int t = 0; t < TC; ++t) {
        unsigned long long w = mw[t * 16 + (tid >> 4)];
        unsigned int bits = (unsigned int)(w >> ((tid & 15) * 4)) & 0xFu;
        float r = rcp[t];
        float4 o;
        o.x = (bits & 1u) ? r : 0.0f;
        o.y = (bits & 2u) ? r : 0.0f;
        o.z = (bits & 4u) ? r : 0.0f;
        o.w = (bits & 8u) ? r : 0.0f;
        outb[t * (DD / 4)] = o;
    }
}

extern "C" void kernel_launch(void* const* d_in, const int* in_sizes, int n_in,
                              void* d_out, int out_size, void* d_ws, size_t ws_size,
                              hipStream_t stream) {
    const float* x         = (const float*)d_in[0];
    const float* threshold = (const float*)d_in[1];
    const float* tau       = (const float*)d_in[2];
    const float* v         = (const float*)d_in[3];
    float* out = (float*)d_out;
    unsigned long long* masks = (unsigned long long*)d_ws;  // B*T*16 u64 = 4.19 MB

    dim3 g1(TT / L1SEG, DD / DT, BB);   // 16 x 4 x 8 = 512 blocks
    lif_spike_kernel<<<g1, 256, 0, stream>>>(x, threshold, tau, v, masks);

    dim3 g2(TT / TC, BB);               // 256 x 8 = 2048 blocks
    lif_norm_kernel<<<g2, 256, 0, stream>>>(masks, out);
}

// Round 3
// 246.141 us; speedup vs baseline: 1.4861x; 1.4861x over previous
//
#include <hip/hip_runtime.h>

#define BB 8
#define TT 4096
#define DD 1024
#define KK 64
#define DT 256        // channels per K1 block (1 thread = 1 channel)
#define CH 16         // rows per staged chunk
#define L1SEG 256     // output rows per K1 block
#define NCH (KK / CH + L1SEG / CH)   // 4 warm-up chunks + 16 compute chunks = 20
#define NSLOT 5       // LDS ring slots (80 KB -> 2 blocks/CU)
#define TC 16         // t-rows per K2 block

// Kernel 1: LDS-ring staged, f64 sliding-window recurrence -> packed spike bits.
// Chunk k covers rows [t0-64 + k*CH, +CH). History row t-64 of chunk k lives in
// chunk k-4. Ring-5 schedule per iteration k:
//   loadChunk(k+1) -> regs; compute chunk k (reads slots k%5 and (k-4)%5);
//   barrier; writeChunk(k+1) -> slot (k+1)%5 == (k-4)%5 (chunk k-4, now dead);
//   barrier.
__global__ __launch_bounds__(256) void lif_spike_kernel(
    const float* __restrict__ x, const float* __restrict__ threshold,
    const float* __restrict__ tau, const float* __restrict__ v0p,
    unsigned long long* __restrict__ masks)
{
    __shared__ float ring[NSLOT][CH][DT];   // 5*16*256*4 = 80 KB
    const int tid   = threadIdx.x;
    const int tseg  = blockIdx.x;
    const int dtile = blockIdx.y;
    const int b     = blockIdx.z;
    const int d     = dtile * DT + tid;
    const int t0    = tseg * L1SEG;

    double tc = (double)tau[d];
    tc = tc < 0.001 ? 0.001 : (tc > 0.999 ? 0.999 : tc);
    const double ltau = log(tc);
    const double c64  = exp(64.0 * ltau);   // tau^64
    const double thr  = (double)threshold[d];
    const double v0   = (double)v0p[d];
    double pw  = exp((double)(t0 + 1) * ltau);
    double acc = 0.0;

    const float* xb = x + ((size_t)b * TT) * DD + dtile * DT;
    const int lane = tid & 63;
    const int wg   = dtile * 4 + (tid >> 6);
    unsigned long long* mrow = masks + ((size_t)b * TT) * 16 + wg;

    float4 rg[4];

    auto loadChunk = [&](int k) {
        const int rstart = t0 - KK + k * CH;
        #pragma unroll
        for (int l = 0; l < 4; ++l) {
            const int f   = l * 256 + tid;   // float4 index within 16x256 chunk
            const int row = f >> 6;          // 64 float4 per row
            const int c4  = f & 63;
            const int rr  = rstart + row;
            if (rr >= 0)
                rg[l] = *(const float4*)(xb + (size_t)rr * DD + c4 * 4);
            else
                rg[l] = make_float4(0.f, 0.f, 0.f, 0.f);
        }
    };
    auto writeChunk = [&](int k) {
        const int s = k % NSLOT;
        #pragma unroll
        for (int l = 0; l < 4; ++l) {
            const int f   = l * 256 + tid;
            const int row = f >> 6;
            const int c4  = f & 63;
            *(float4*)&ring[s][row][c4 * 4] = rg[l];
        }
    };

    // Prologue: stage chunks 0..4 (rows t0-64 .. t0+15) into slots 0..4
    #pragma unroll
    for (int k = 0; k < NSLOT; ++k) { loadChunk(k); writeChunk(k); }
    __syncthreads();

    // Warm-up: 64 rows (chunks 0..3) build the running window sum
    #pragma unroll
    for (int k = 0; k < KK / CH; ++k) {
        #pragma unroll
        for (int i = 0; i < CH; ++i)
            acc = fma(tc, acc, (double)ring[k][i][tid]);
    }

    // Main loop: compute chunk k, stage chunk k+1
    for (int k = KK / CH; k < NCH; ++k) {
        const bool stage = (k + 1 < NCH);
        if (stage) loadChunk(k + 1);
        const int cs = k % NSLOT, hs = (k - 4) % NSLOT;
        const int tbase = t0 + (k - KK / CH) * CH;
        #pragma unroll
        for (int i = 0; i < CH; ++i) {
            const float xv = ring[cs][i][tid];
            const float ov = ring[hs][i][tid];
            acc = fma(tc, acc, (double)xv);      // + x[t]
            acc = fma(-c64, (double)ov, acc);    // - tau^64 * x[t-64]
            const double vint = fma(v0, pw, acc);
            pw *= tc;
            const unsigned long long m = __ballot(vint >= thr);
            if (lane == 0) mrow[(size_t)(tbase + i) * 16] = m;
        }
        __syncthreads();
        if (stage) writeChunk(k + 1);
        __syncthreads();
    }
}

// Kernel 2: popcount -> denom -> normalized float4 output
__global__ __launch_bounds__(256) void lif_norm_kernel(
    const unsigned long long* __restrict__ masks,
    float* __restrict__ out)
{
    __shared__ unsigned long long mw[TC * 16];
    __shared__ float rcp[TC];
    const int tid    = threadIdx.x;
    const int tchunk = blockIdx.x;
    const int b      = blockIdx.y;
    const int tbase  = tchunk * TC;

    mw[tid] = masks[((size_t)b * TT + tbase) * 16 + tid];
    __syncthreads();

    if (tid < TC) {
        int cnt = 0;
        #pragma unroll
        for (int w = 0; w < 16; ++w) cnt += __popcll(mw[tid * 16 + w]);
        rcp[tid] = 1.0f / fmaxf((float)cnt, 1.0f);
    }
    __syncthreads();

    float4* outb = (float4*)(out + ((size_t)b * TT + tbase) * DD) + tid;
    #pragma unroll
    for (int t = 0; t < TC; ++t) {
        const unsigned long long w = mw[t * 16 + (tid >> 4)];
        const unsigned int bits = (unsigned int)(w >> ((tid & 15) * 4)) & 0xFu;
        const float r = rcp[t];
        float4 o;
        o.x = (bits & 1u) ? r : 0.0f;
        o.y = (bits & 2u) ? r : 0.0f;
        o.z = (bits & 4u) ? r : 0.0f;
        o.w = (bits & 8u) ? r : 0.0f;
        outb[t * (DD / 4)] = o;
    }
}

extern "C" void kernel_launch(void* const* d_in, const int* in_sizes, int n_in,
                              void* d_out, int out_size, void* d_ws, size_t ws_size,
                              hipStream_t stream) {
    const float* x         = (const float*)d_in[0];
    const float* threshold = (const float*)d_in[1];
    const float* tau       = (const float*)d_in[2];
    const float* v         = (const float*)d_in[3];
    float* out = (float*)d_out;
    unsigned long long* masks = (unsigned long long*)d_ws;  // B*T*16 u64 = 4.19 MB

    dim3 g1(TT / L1SEG, DD / DT, BB);   // 16 x 4 x 8 = 512 blocks
    lif_spike_kernel<<<g1, 256, 0, stream>>>(x, threshold, tau, v, masks);

    dim3 g2(TT / TC, BB);               // 256 x 8 = 2048 blocks
    lif_norm_kernel<<<g2, 256, 0, stream>>>(masks, out);
}